// Round 1
// baseline (1419.017 us; speedup 1.0000x reference)
//
#include <hip/hip_runtime.h>
#include <math.h>

// Problem constants (from reference setup_inputs)
#define BB 8
#define CC 3
#define DD 24
#define HH 128
#define WW 128
#define OCC 16
#define DOUT 22   // 24 - 2
#define HOUT 126  // 128 - 2
#define WOUT 126  // 128 - 2

// One thread per output pixel (b, h, w); computes all 16 output channels:
// conv3d (VALID) -> min over 22 depths -> softmax over 16 channels.
// 16 parallel FMA chains per thread for ILP; weights are wave-uniform
// (compile-time offsets from a uniform pointer) -> scalar loads.
__global__ __launch_bounds__(128) void conv_min_softmax_kernel(
    const float* __restrict__ x, const float* __restrict__ wt,
    float* __restrict__ out) {
  const int w = threadIdx.x;
  const int h = blockIdx.y;
  const int b = blockIdx.z;
  if (w >= WOUT) return;

  // Base pointer at (b, c=0, d=0, h, w).
  const float* xb = x + (((size_t)b * CC * DD) * HH + h) * (size_t)WW + w;
  // offset(c, d, kh, kw) = ((c*DD + d)*HH + kh)*WW + kw

  float ymin[OCC];
#pragma unroll
  for (int oc = 0; oc < OCC; ++oc) ymin[oc] = INFINITY;

  for (int dz = 0; dz < DOUT; ++dz) {  // NOT unrolled: keep body ~1.3k FMA
    float y[OCC];
#pragma unroll
    for (int oc = 0; oc < OCC; ++oc) y[oc] = 0.f;

    const float* xd = xb + dz * (HH * WW);
#pragma unroll
    for (int c = 0; c < CC; ++c) {
#pragma unroll
      for (int kd = 0; kd < 3; ++kd) {
#pragma unroll
        for (int kh = 0; kh < 3; ++kh) {
#pragma unroll
          for (int kw = 0; kw < 3; ++kw) {
            const float xv = xd[((c * DD + kd) * HH + kh) * WW + kw];
            const int widx = c * 27 + kd * 9 + kh * 3 + kw;
#pragma unroll
            for (int oc = 0; oc < OCC; ++oc) {
              y[oc] = fmaf(xv, wt[oc * 81 + widx], y[oc]);
            }
          }
        }
      }
    }
#pragma unroll
    for (int oc = 0; oc < OCC; ++oc) ymin[oc] = fminf(ymin[oc], y[oc]);
  }

  // Softmax over the 16 channels (all in registers).
  float m = ymin[0];
#pragma unroll
  for (int oc = 1; oc < OCC; ++oc) m = fmaxf(m, ymin[oc]);
  float e[OCC];
  float sum = 0.f;
#pragma unroll
  for (int oc = 0; oc < OCC; ++oc) {
    e[oc] = __expf(ymin[oc] - m);
    sum += e[oc];
  }
  const float inv = 1.f / sum;
#pragma unroll
  for (int oc = 0; oc < OCC; ++oc) {
    out[(((size_t)b * OCC + oc) * HOUT + h) * WOUT + w] = e[oc] * inv;
  }
}

extern "C" void kernel_launch(void* const* d_in, const int* in_sizes, int n_in,
                              void* d_out, int out_size, void* d_ws, size_t ws_size,
                              hipStream_t stream) {
  const float* x = (const float*)d_in[0];
  const float* wt = (const float*)d_in[1];
  float* out = (float*)d_out;

  dim3 grid(1, HOUT, BB);   // 126 * 8 = 1008 blocks
  dim3 block(128, 1, 1);    // covers WOUT=126 (2 idle lanes in wave 1)
  conv_min_softmax_kernel<<<grid, block, 0, stream>>>(x, wt, out);
}